// Round 10
// baseline (1134.300 us; speedup 1.0000x reference)
//
#include <hip/hip_runtime.h>
#include <math.h>

#define PI_F 3.14159265358979323846f

typedef float f2 __attribute__((ext_vector_type(2)));

__device__ __forceinline__ f2 pkfma(f2 a, f2 b, f2 c) {
    return __builtin_elementwise_fma(a, b, c);
}
__device__ __forceinline__ f2 sp(float v) { f2 r; r.x = v; r.y = v; return r; }
__device__ __forceinline__ f2 mk2(float a, float b) { f2 r; r.x = a; r.y = b; return r; }

// bf16-pair -> f2 (bit-exact bf16->f32 is a 16-bit shift)
__device__ __forceinline__ f2 up2(unsigned u) {
    f2 r;
    r.x = __uint_as_float(u << 16);
    r.y = __uint_as_float(u & 0xFFFF0000u);
    return r;
}

// Sum v[hl&7] over the lane's OWN 32-lane half (two pixels per wave).
__device__ __forceinline__ float fold8h(float v0, float v1, float v2, float v3,
                                        float v4, float v5, float v6, float v7,
                                        int hl) {
    const bool b4 = (hl & 4) != 0;
    float k0 = b4 ? v4 : v0, g0 = b4 ? v0 : v4;
    float k1 = b4 ? v5 : v1, g1 = b4 ? v1 : v5;
    float k2 = b4 ? v6 : v2, g2 = b4 ? v2 : v6;
    float k3 = b4 ? v7 : v3, g3 = b4 ? v3 : v7;
    k0 += __shfl_xor(g0, 4, 64);
    k1 += __shfl_xor(g1, 4, 64);
    k2 += __shfl_xor(g2, 4, 64);
    k3 += __shfl_xor(g3, 4, 64);
    const bool b2 = (hl & 2) != 0;
    float m0 = b2 ? k2 : k0, n0 = b2 ? k0 : k2;
    float m1 = b2 ? k3 : k1, n1 = b2 ? k1 : k3;
    m0 += __shfl_xor(n0, 2, 64);
    m1 += __shfl_xor(n1, 2, 64);
    const bool b1_ = (hl & 1) != 0;
    float q = b1_ ? m1 : m0, r = b1_ ? m0 : m1;
    q += __shfl_xor(r, 1, 64);
    q += __shfl_xor(q, 8, 64);
    q += __shfl_xor(q, 16, 64);
    return q;
}

// Repack w3 [9][64][8] -> ws[tap][hl][j] (channel-pair f2) and wr [128][8]
// -> tan/nor pair tables. 2816 f2 elements.
__global__ void repack_kernel(const float* __restrict__ w3,
                              const float* __restrict__ wr,
                              f2* __restrict__ ws) {
    int t = blockIdx.x * 256 + threadIdx.x;
    if (t < 2304) {
        int tap = t >> 8, rem = t & 255, hl = rem >> 3, j = rem & 7;
        f2 v; v.x = w3[((tap << 6) + (hl << 1)) * 8 + j];
        v.y = w3[((tap << 6) + (hl << 1) + 1) * 8 + j];
        ws[t] = v;
    } else if (t < 2560) {
        int rem = t - 2304, hl = rem >> 3, j = rem & 7;
        f2 v; v.x = wr[(hl << 1) * 8 + j];
        v.y = wr[((hl << 1) + 1) * 8 + j];
        ws[t] = v;
    } else if (t < 2816) {
        int rem = t - 2560, hl = rem >> 3, j = rem & 7;
        f2 v; v.x = wr[(64 + (hl << 1)) * 8 + j];
        v.y = wr[(64 + (hl << 1) + 1) * 8 + j];
        ws[t] = v;
    }
}

// bf16 LDS tile: 11 rows x 17 cols x 32 u32 (64 ch as bf16 pairs) = 23936 B.
#define TR 11
#define TC 17

// Bilinear sample from the bf16 tile. Weights from CLIPPED integer global
// corner coords (faithful to reference). Left-edge clip (x0<0) zeroes the
// x-weights (true contribution is exactly 0 there); right-edge x dup and all
// y clips are handled by clamped staging / same-row reads.
__device__ __forceinline__ f2 samp(const char* tb, float cy, float cx,
                                   int ybase, int xbase, unsigned laneoff4,
                                   f2 acc) {
    int y0 = (int)floorf(cy), x0 = (int)floorf(cx);
    int y0i = min(max(y0, 0), 255);
    int y1i = min(max(y0 + 1, 0), 255);
    int x0i = min(max(x0, 0), 255);
    int x1i = min(max(x0 + 1, 0), 255);
    float wy0 = (float)y1i - cy, wy1 = cy - (float)y0i;
    float wx0 = (float)x1i - cx, wx1 = cx - (float)x0i;
    if (x0 < 0) { wx0 = 0.f; wx1 = 0.f; }
    unsigned rb0 = (unsigned)((y0i - ybase) * TC);
    unsigned rb1 = (unsigned)((y1i - ybase) * TC);
    unsigned c0 = (unsigned)(x0i - xbase);
    unsigned c1 = (unsigned)(x1i - xbase);
    unsigned a00 = ((rb0 + c0) << 7) + laneoff4;
    unsigned a10 = ((rb1 + c0) << 7) + laneoff4;
    unsigned a01 = ((rb0 + c1) << 7) + laneoff4;
    unsigned a11 = ((rb1 + c1) << 7) + laneoff4;
    unsigned u00 = *(const unsigned*)(tb + a00);
    unsigned u10 = *(const unsigned*)(tb + a10);
    unsigned u01 = *(const unsigned*)(tb + a01);
    unsigned u11 = *(const unsigned*)(tb + a11);
    acc = pkfma(sp(wx0 * wy0), up2(u00), acc);
    acc = pkfma(sp(wx0 * wy1), up2(u10), acc);
    acc = pkfma(sp(wx1 * wy0), up2(u01), acc);
    acc = pkfma(sp(wx1 * wy1), up2(u11), acc);
    return acc;
}

// Fused kernel: block = 16 px (2 rows x 8 cols), 8 waves, one pixel PAIR per
// wave (lanes 0-31 px A, 32-63 px B, lane = channel pair). Pool samples come
// from a bf16 LDS tile; conv taps + center value come from global fp32.
__global__ __launch_bounds__(512) void oca_kernel(
    const float* __restrict__ x,
    const float* __restrict__ b3, const float* __restrict__ w1,
    const float* __restrict__ b1, const float* __restrict__ br,
    const float* __restrict__ we, const float* __restrict__ be,
    const f2* __restrict__ ws,
    float* __restrict__ out) {
    __shared__ unsigned tile[TR * TC * 32];
    const int tid = threadIdx.x;
    const int lane = tid & 63;
    const int hl = lane & 31;
    const int half = lane >> 5;
    const int wid = __builtin_amdgcn_readfirstlane(tid >> 6);   // 0..7

    const unsigned beta = blockIdx.x;
    const int b   = beta >> 12;            // 128*32 tiles per batch
    const int ty  = (beta >> 5) & 127;
    const int tx  = beta & 31;
    const int yq0 = ty << 1;
    const int xq0 = tx << 3;
    const int ybase = yq0 - 4;
    const int xbase = xq0 - 4;
    const float* xb = x + ((size_t)b << 22);

    // ---- stage bf16 tile: 16 threads/px, float4 read -> cvt_pk -> b64 write ----
    {
        const int g    = tid >> 4;          // 0..31
        const int subf = (tid & 15) << 2;   // f32 channel offset
        for (int p = g; p < TR * TC; p += 32) {
            int pr = p / TC;
            int pc = p - pr * TC;
            int gy = min(max(ybase + pr, 0), 255);
            int gx = min(max(xbase + pc, 0), 255);
            float4 v = *(const float4*)(xb + (size_t)(((gy << 8) + gx) << 6) + subf);
            unsigned u0, u1;
            asm("v_cvt_pk_bf16_f32 %0, %1, %2" : "=v"(u0) : "v"(v.x), "v"(v.y));
            asm("v_cvt_pk_bf16_f32 %0, %1, %2" : "=v"(u1) : "v"(v.z), "v"(v.w));
            uint2 wv; wv.x = u0; wv.y = u1;
            *(uint2*)&tile[p * 32 + (subf >> 1)] = wv;
        }
    }
    __syncthreads();

    const int yqw = yq0 + (wid >> 2);                 // this wave's pixel row
    const int xql = xq0 + ((wid & 3) << 1) + half;    // this lane's pixel col
    const unsigned laneoff8 = (unsigned)hl << 3;      // fp32 ch-pair byte off
    const unsigned laneoff4 = (unsigned)hl << 2;      // bf16 ch-pair byte off
    const char* tb = (const char*)tile;
    const char* xbb = (const char*)xb;

    // ---- conv3x3 from GLOBAL fp32 (zero-padded borders) ----
    f2 a0 = sp(0.f), a1 = sp(0.f), a2 = sp(0.f), a3 = sp(0.f);
    f2 a4 = sp(0.f), a5 = sp(0.f), a6 = sp(0.f), a7 = sp(0.f);
    f2 xc2 = sp(0.f);
#pragma unroll
    for (int dy = -1; dy <= 1; ++dy) {
#pragma unroll
        for (int dx = -1; dx <= 1; ++dx) {
            int yy = yqw + dy;
            int xx = xql + dx;
            bool valid = ((unsigned)yy < 256u) && ((unsigned)xx < 256u);
            unsigned gy = (unsigned)min(max(yy, 0), 255);
            unsigned gx = (unsigned)min(max(xx, 0), 255);
            f2 xv = *(const f2*)(xbb + (((gy << 8) + gx) << 8) + laneoff8);
            xv = valid ? xv : sp(0.f);
            if (dy == 0 && dx == 0) xc2 = xv;
            const int tap = (dy + 1) * 3 + (dx + 1);
            const float4* wq = (const float4*)(ws + (tap << 8) + (hl << 3));
            float4 q0 = wq[0], q1 = wq[1], q2 = wq[2], q3 = wq[3];
            a0 = pkfma(xv, mk2(q0.x, q0.y), a0);
            a1 = pkfma(xv, mk2(q0.z, q0.w), a1);
            a2 = pkfma(xv, mk2(q1.x, q1.y), a2);
            a3 = pkfma(xv, mk2(q1.z, q1.w), a3);
            a4 = pkfma(xv, mk2(q2.x, q2.y), a4);
            a5 = pkfma(xv, mk2(q2.z, q2.w), a5);
            a6 = pkfma(xv, mk2(q3.x, q3.y), a6);
            a7 = pkfma(xv, mk2(q3.z, q3.w), a7);
        }
    }
    const int j = hl & 7;
    float hsum = fold8h(a0.x + a0.y, a1.x + a1.y, a2.x + a2.y, a3.x + a3.y,
                        a4.x + a4.y, a5.x + a5.y, a6.x + a6.y, a7.x + a7.y, hl);
    float h_l = fmaxf(hsum + b3[j], 0.f);

    // ---- theta (per half-wave) ----
    float zp = h_l * w1[j];
    zp += __shfl_xor(zp, 1, 64);
    zp += __shfl_xor(zp, 2, 64);
    zp += __shfl_xor(zp, 4, 64);
    float z = zp + b1[0];
    float theta = PI_F * __builtin_amdgcn_rcpf(1.f + __expf(-z));
    float vcos = __cosf(theta);
    float vsin = __sinf(theta);

    // ---- oriented pooling from bf16 LDS tile ----
    // t=0 (both dirs) is exactly the center pixel, or 0 on the last row/col.
    const float fy = (float)yqw, fx = (float)xql;
    bool interior = (yqw < 255) && (xql < 255);
    f2 t0c = interior ? xc2 : sp(0.f);
    f2 at0 = t0c, at1 = sp(0.f), an0 = t0c, an1 = sp(0.f);
#pragma unroll
    for (int t = -4; t <= 4; ++t) {
        if (t == 0) continue;
        float tf = (float)t;
        f2& accT = (t & 1) ? at1 : at0;
        f2& accN = (t & 1) ? an1 : an0;
        accT = samp(tb, fmaf(tf, vsin, fy), fmaf(tf, vcos, fx),
                    ybase, xbase, laneoff4, accT);
        accN = samp(tb, fmaf(tf, vcos, fy), fmaf(-tf, vsin, fx),
                    ybase, xbase, laneoff4, accN);
    }
    f2 tan2 = mk2((at0.x + at1.x) * (1.f / 9.f), (at0.y + at1.y) * (1.f / 9.f));
    f2 nor2 = mk2((an0.x + an1.x) * (1.f / 9.f), (an0.y + an1.y) * (1.f / 9.f));

    // ---- r = relu(wr . [tan;nor] + br) ----
    const f2* wrp = ws + 2304 + (hl << 3);
    const f2* wrn = ws + 2560 + (hl << 3);
    f2 p0 = pkfma(tan2, wrp[0], sp(0.f)); p0 = pkfma(nor2, wrn[0], p0);
    f2 p1 = pkfma(tan2, wrp[1], sp(0.f)); p1 = pkfma(nor2, wrn[1], p1);
    f2 p2 = pkfma(tan2, wrp[2], sp(0.f)); p2 = pkfma(nor2, wrn[2], p2);
    f2 p3 = pkfma(tan2, wrp[3], sp(0.f)); p3 = pkfma(nor2, wrn[3], p3);
    f2 p4 = pkfma(tan2, wrp[4], sp(0.f)); p4 = pkfma(nor2, wrn[4], p4);
    f2 p5 = pkfma(tan2, wrp[5], sp(0.f)); p5 = pkfma(nor2, wrn[5], p5);
    f2 p6 = pkfma(tan2, wrp[6], sp(0.f)); p6 = pkfma(nor2, wrn[6], p6);
    f2 p7 = pkfma(tan2, wrp[7], sp(0.f)); p7 = pkfma(nor2, wrn[7], p7);
    float rsum = fold8h(p0.x + p0.y, p1.x + p1.y, p2.x + p2.y, p3.x + p3.y,
                        p4.x + p4.y, p5.x + p5.y, p6.x + p6.y, p7.x + p7.y, hl);
    float r_l = fmaxf(rsum + br[j], 0.f);   // lane holds r[j], j = hl&7

    // broadcast within half: slot m holds r[j ^ m]
    float rb0 = r_l;
    float rb1 = __shfl_xor(rb0, 1, 64);
    float rb2 = __shfl_xor(rb0, 2, 64);
    float rb3 = __shfl_xor(rb1, 2, 64);
    float rb4 = __shfl_xor(rb0, 4, 64);
    float rb5 = __shfl_xor(rb1, 4, 64);
    float rb6 = __shfl_xor(rb2, 4, 64);
    float rb7 = __shfl_xor(rb3, 4, 64);

    // ---- w = sigmoid(we . r + be), packed channel pairs ----
    const char* web = (const char*)we;
    unsigned voff = ((unsigned)j << 9) | laneoff8;
    f2 zt2 = *(const f2*)((const char*)be + laneoff8);
    f2 zn2 = *(const f2*)((const char*)be + 256 + laneoff8);
#pragma unroll
    for (int m = 0; m < 8; ++m) {
        unsigned vm = voff ^ ((unsigned)m << 9);
        float rbm = (m == 0) ? rb0 : (m == 1) ? rb1 : (m == 2) ? rb2 : (m == 3) ? rb3
                  : (m == 4) ? rb4 : (m == 5) ? rb5 : (m == 6) ? rb6 : rb7;
        zt2 = pkfma(sp(rbm), *(const f2*)(web + vm), zt2);
        zn2 = pkfma(sp(rbm), *(const f2*)(web + vm + 256), zn2);
    }
    f2 wt2, wn2;
    wt2.x = __builtin_amdgcn_rcpf(1.f + __expf(-zt2.x));
    wt2.y = __builtin_amdgcn_rcpf(1.f + __expf(-zt2.y));
    wn2.x = __builtin_amdgcn_rcpf(1.f + __expf(-zn2.x));
    wn2.y = __builtin_amdgcn_rcpf(1.f + __expf(-zn2.y));

    // out byte = (pixelA_index << 8) + (lane << 3); halves = adjacent pixels
    f2 o = mk2((wt2.x + wn2.x) * xc2.x, (wt2.y + wn2.y) * xc2.y);
    size_t pixA = ((size_t)b << 16) + ((size_t)yqw << 8) + (size_t)(xq0 + ((wid & 3) << 1));
    *(f2*)((char*)out + (pixA << 8) + ((unsigned)lane << 3)) = o;
}

extern "C" void kernel_launch(void* const* d_in, const int* in_sizes, int n_in,
                              void* d_out, int out_size, void* d_ws, size_t ws_size,
                              hipStream_t stream) {
    const float* x  = (const float*)d_in[0];
    const float* w3 = (const float*)d_in[1];
    const float* b3 = (const float*)d_in[2];
    const float* w1 = (const float*)d_in[3];
    const float* b1 = (const float*)d_in[4];
    const float* wr = (const float*)d_in[5];
    const float* br = (const float*)d_in[6];
    const float* we = (const float*)d_in[7];
    const float* be = (const float*)d_in[8];
    float* out = (float*)d_out;
    f2* ws = (f2*)d_ws;

    repack_kernel<<<11, 256, 0, stream>>>(w3, wr, ws);

    // 524288 pixels / 16 per block = 32768 blocks of 512 threads
    dim3 grid(32768), block(512);
    oca_kernel<<<grid, block, 0, stream>>>(x, b3, w1, b1, br, we, be, ws, out);
}

// Round 11
// 1132.244 us; speedup vs baseline: 1.0018x; 1.0018x over previous
//
#include <hip/hip_runtime.h>
#include <math.h>

#define PI_F 3.14159265358979323846f

typedef float f2 __attribute__((ext_vector_type(2)));

__device__ __forceinline__ f2 pkfma(f2 a, f2 b, f2 c) {
    return __builtin_elementwise_fma(a, b, c);
}
__device__ __forceinline__ f2 sp(float v) { f2 r; r.x = v; r.y = v; return r; }
__device__ __forceinline__ f2 mk2(float a, float b) { f2 r; r.x = a; r.y = b; return r; }

// bf16-pair -> f2 (bit-exact bf16->f32 is a 16-bit shift)
__device__ __forceinline__ f2 up2(unsigned u) {
    f2 r;
    r.x = __uint_as_float(u << 16);
    r.y = __uint_as_float(u & 0xFFFF0000u);
    return r;
}

// Sum v[hl&7] over the lane's OWN 32-lane half (two pixels per wave).
__device__ __forceinline__ float fold8h(float v0, float v1, float v2, float v3,
                                        float v4, float v5, float v6, float v7,
                                        int hl) {
    const bool b4 = (hl & 4) != 0;
    float k0 = b4 ? v4 : v0, g0 = b4 ? v0 : v4;
    float k1 = b4 ? v5 : v1, g1 = b4 ? v1 : v5;
    float k2 = b4 ? v6 : v2, g2 = b4 ? v2 : v6;
    float k3 = b4 ? v7 : v3, g3 = b4 ? v3 : v7;
    k0 += __shfl_xor(g0, 4, 64);
    k1 += __shfl_xor(g1, 4, 64);
    k2 += __shfl_xor(g2, 4, 64);
    k3 += __shfl_xor(g3, 4, 64);
    const bool b2 = (hl & 2) != 0;
    float m0 = b2 ? k2 : k0, n0 = b2 ? k0 : k2;
    float m1 = b2 ? k3 : k1, n1 = b2 ? k1 : k3;
    m0 += __shfl_xor(n0, 2, 64);
    m1 += __shfl_xor(n1, 2, 64);
    const bool b1_ = (hl & 1) != 0;
    float q = b1_ ? m1 : m0, r = b1_ ? m0 : m1;
    q += __shfl_xor(r, 1, 64);
    q += __shfl_xor(q, 8, 64);
    q += __shfl_xor(q, 16, 64);
    return q;
}

// Repack w3 [9][64][8] -> ws[tap][hl][j] (channel-pair f2) and wr [128][8]
// -> tan/nor pair tables. 2816 f2 elements.
__global__ void repack_kernel(const float* __restrict__ w3,
                              const float* __restrict__ wr,
                              f2* __restrict__ ws) {
    int t = blockIdx.x * 256 + threadIdx.x;
    if (t < 2304) {
        int tap = t >> 8, rem = t & 255, hl = rem >> 3, j = rem & 7;
        f2 v; v.x = w3[((tap << 6) + (hl << 1)) * 8 + j];
        v.y = w3[((tap << 6) + (hl << 1) + 1) * 8 + j];
        ws[t] = v;
    } else if (t < 2560) {
        int rem = t - 2304, hl = rem >> 3, j = rem & 7;
        f2 v; v.x = wr[(hl << 1) * 8 + j];
        v.y = wr[((hl << 1) + 1) * 8 + j];
        ws[t] = v;
    } else if (t < 2816) {
        int rem = t - 2560, hl = rem >> 3, j = rem & 7;
        f2 v; v.x = wr[(64 + (hl << 1)) * 8 + j];
        v.y = wr[(64 + (hl << 1) + 1) * 8 + j];
        ws[t] = v;
    }
}

// bf16 LDS tile: 11 rows x 13 cols x 32 u32 (64 ch as bf16 pairs) = 18304 B.
#define TR 11
#define TC 13

// Bilinear sample from the bf16 tile. Weights from CLIPPED integer global
// corner coords (faithful to reference). Left-edge clip (x0<0) zeroes the
// x-weights (true contribution is exactly 0 there); right-edge x dup and all
// y clips are handled by clamped staging / same-row reads.
__device__ __forceinline__ f2 samp(const char* tb, float cy, float cx,
                                   int ybase, int xbase, unsigned laneoff4,
                                   f2 acc) {
    int y0 = (int)floorf(cy), x0 = (int)floorf(cx);
    int y0i = min(max(y0, 0), 255);
    int y1i = min(max(y0 + 1, 0), 255);
    int x0i = min(max(x0, 0), 255);
    int x1i = min(max(x0 + 1, 0), 255);
    float wy0 = (float)y1i - cy, wy1 = cy - (float)y0i;
    float wx0 = (float)x1i - cx, wx1 = cx - (float)x0i;
    if (x0 < 0) { wx0 = 0.f; wx1 = 0.f; }
    unsigned rb0 = (unsigned)((y0i - ybase) * TC);
    unsigned rb1 = (unsigned)((y1i - ybase) * TC);
    unsigned c0 = (unsigned)(x0i - xbase);
    unsigned c1 = (unsigned)(x1i - xbase);
    unsigned a00 = ((rb0 + c0) << 7) + laneoff4;
    unsigned a10 = ((rb1 + c0) << 7) + laneoff4;
    unsigned a01 = ((rb0 + c1) << 7) + laneoff4;
    unsigned a11 = ((rb1 + c1) << 7) + laneoff4;
    unsigned u00 = *(const unsigned*)(tb + a00);
    unsigned u10 = *(const unsigned*)(tb + a10);
    unsigned u01 = *(const unsigned*)(tb + a01);
    unsigned u11 = *(const unsigned*)(tb + a11);
    acc = pkfma(sp(wx0 * wy0), up2(u00), acc);
    acc = pkfma(sp(wx0 * wy1), up2(u10), acc);
    acc = pkfma(sp(wx1 * wy0), up2(u01), acc);
    acc = pkfma(sp(wx1 * wy1), up2(u11), acc);
    return acc;
}

// Fused kernel: block = 256 threads = 4 waves = 8 px (2 rows x 4 cols), one
// pixel PAIR per wave (lanes 0-31 px A, 32-63 px B, lane = channel pair).
// Pool samples come from a bf16 LDS tile; conv taps + center from global fp32.
// 256-thread blocks: rounds 9-10's 512-thread blocks capped at 1 block/CU
// (26% occupancy regardless of LDS size) — block size was the limiter suspect.
__global__ __launch_bounds__(256) void oca_kernel(
    const float* __restrict__ x,
    const float* __restrict__ b3, const float* __restrict__ w1,
    const float* __restrict__ b1, const float* __restrict__ br,
    const float* __restrict__ we, const float* __restrict__ be,
    const f2* __restrict__ ws,
    float* __restrict__ out) {
    __shared__ unsigned tile[TR * TC * 32];
    const int tid = threadIdx.x;
    const int lane = tid & 63;
    const int hl = lane & 31;
    const int half = lane >> 5;
    const int wid = __builtin_amdgcn_readfirstlane(tid >> 6);   // 0..3

    const unsigned beta = blockIdx.x;
    const int b   = beta >> 13;            // 128 y-tiles * 64 x-tiles per batch
    const int ty  = (beta >> 6) & 127;
    const int tx  = beta & 63;
    const int yq0 = ty << 1;
    const int xq0 = tx << 2;
    const int ybase = yq0 - 4;
    const int xbase = xq0 - 4;
    const float* xb = x + ((size_t)b << 22);

    // ---- stage bf16 tile: 16 threads/px, float4 read -> cvt_pk -> b64 write ----
    {
        const int g    = tid >> 4;          // 0..15
        const int subf = (tid & 15) << 2;   // f32 channel offset
        for (int p = g; p < TR * TC; p += 16) {
            int pr = p / TC;
            int pc = p - pr * TC;
            int gy = min(max(ybase + pr, 0), 255);
            int gx = min(max(xbase + pc, 0), 255);
            float4 v = *(const float4*)(xb + (size_t)(((gy << 8) + gx) << 6) + subf);
            unsigned u0, u1;
            asm("v_cvt_pk_bf16_f32 %0, %1, %2" : "=v"(u0) : "v"(v.x), "v"(v.y));
            asm("v_cvt_pk_bf16_f32 %0, %1, %2" : "=v"(u1) : "v"(v.z), "v"(v.w));
            uint2 wv; wv.x = u0; wv.y = u1;
            *(uint2*)&tile[p * 32 + (subf >> 1)] = wv;
        }
    }
    __syncthreads();

    const int yqw = yq0 + (wid >> 1);                 // this wave's pixel row
    const int xql = xq0 + ((wid & 1) << 1) + half;    // this lane's pixel col
    const unsigned laneoff8 = (unsigned)hl << 3;      // fp32 ch-pair byte off
    const unsigned laneoff4 = (unsigned)hl << 2;      // bf16 ch-pair byte off
    const char* tb = (const char*)tile;
    const char* xbb = (const char*)xb;

    // ---- conv3x3 from GLOBAL fp32 (zero-padded borders) ----
    f2 a0 = sp(0.f), a1 = sp(0.f), a2 = sp(0.f), a3 = sp(0.f);
    f2 a4 = sp(0.f), a5 = sp(0.f), a6 = sp(0.f), a7 = sp(0.f);
    f2 xc2 = sp(0.f);
#pragma unroll
    for (int dy = -1; dy <= 1; ++dy) {
#pragma unroll
        for (int dx = -1; dx <= 1; ++dx) {
            int yy = yqw + dy;
            int xx = xql + dx;
            bool valid = ((unsigned)yy < 256u) && ((unsigned)xx < 256u);
            unsigned gy = (unsigned)min(max(yy, 0), 255);
            unsigned gx = (unsigned)min(max(xx, 0), 255);
            f2 xv = *(const f2*)(xbb + (((gy << 8) + gx) << 8) + laneoff8);
            xv = valid ? xv : sp(0.f);
            if (dy == 0 && dx == 0) xc2 = xv;
            const int tap = (dy + 1) * 3 + (dx + 1);
            const float4* wq = (const float4*)(ws + (tap << 8) + (hl << 3));
            {   // 2 float4s at a time to limit live registers
                float4 q0 = wq[0], q1 = wq[1];
                a0 = pkfma(xv, mk2(q0.x, q0.y), a0);
                a1 = pkfma(xv, mk2(q0.z, q0.w), a1);
                a2 = pkfma(xv, mk2(q1.x, q1.y), a2);
                a3 = pkfma(xv, mk2(q1.z, q1.w), a3);
            }
            {
                float4 q2 = wq[2], q3 = wq[3];
                a4 = pkfma(xv, mk2(q2.x, q2.y), a4);
                a5 = pkfma(xv, mk2(q2.z, q2.w), a5);
                a6 = pkfma(xv, mk2(q3.x, q3.y), a6);
                a7 = pkfma(xv, mk2(q3.z, q3.w), a7);
            }
        }
    }
    const int j = hl & 7;
    float hsum = fold8h(a0.x + a0.y, a1.x + a1.y, a2.x + a2.y, a3.x + a3.y,
                        a4.x + a4.y, a5.x + a5.y, a6.x + a6.y, a7.x + a7.y, hl);
    float h_l = fmaxf(hsum + b3[j], 0.f);

    // ---- theta (per half-wave) ----
    float zp = h_l * w1[j];
    zp += __shfl_xor(zp, 1, 64);
    zp += __shfl_xor(zp, 2, 64);
    zp += __shfl_xor(zp, 4, 64);
    float z = zp + b1[0];
    float theta = PI_F * __builtin_amdgcn_rcpf(1.f + __expf(-z));
    float vcos = __cosf(theta);
    float vsin = __sinf(theta);

    // ---- oriented pooling from bf16 LDS tile ----
    // t=0 (both dirs) is exactly the center pixel, or 0 on the last row/col.
    const float fy = (float)yqw, fx = (float)xql;
    bool interior = (yqw < 255) && (xql < 255);
    f2 t0c = interior ? xc2 : sp(0.f);
    f2 at0 = t0c, at1 = sp(0.f), an0 = t0c, an1 = sp(0.f);
#pragma unroll
    for (int t = -4; t <= 4; ++t) {
        if (t == 0) continue;
        float tf = (float)t;
        f2& accT = (t & 1) ? at1 : at0;
        f2& accN = (t & 1) ? an1 : an0;
        accT = samp(tb, fmaf(tf, vsin, fy), fmaf(tf, vcos, fx),
                    ybase, xbase, laneoff4, accT);
        accN = samp(tb, fmaf(tf, vcos, fy), fmaf(-tf, vsin, fx),
                    ybase, xbase, laneoff4, accN);
    }
    f2 tan2 = mk2((at0.x + at1.x) * (1.f / 9.f), (at0.y + at1.y) * (1.f / 9.f));
    f2 nor2 = mk2((an0.x + an1.x) * (1.f / 9.f), (an0.y + an1.y) * (1.f / 9.f));

    // ---- r = relu(wr . [tan;nor] + br) ----
    const f2* wrp = ws + 2304 + (hl << 3);
    const f2* wrn = ws + 2560 + (hl << 3);
    f2 p0 = pkfma(tan2, wrp[0], sp(0.f)); p0 = pkfma(nor2, wrn[0], p0);
    f2 p1 = pkfma(tan2, wrp[1], sp(0.f)); p1 = pkfma(nor2, wrn[1], p1);
    f2 p2 = pkfma(tan2, wrp[2], sp(0.f)); p2 = pkfma(nor2, wrn[2], p2);
    f2 p3 = pkfma(tan2, wrp[3], sp(0.f)); p3 = pkfma(nor2, wrn[3], p3);
    f2 p4 = pkfma(tan2, wrp[4], sp(0.f)); p4 = pkfma(nor2, wrn[4], p4);
    f2 p5 = pkfma(tan2, wrp[5], sp(0.f)); p5 = pkfma(nor2, wrn[5], p5);
    f2 p6 = pkfma(tan2, wrp[6], sp(0.f)); p6 = pkfma(nor2, wrn[6], p6);
    f2 p7 = pkfma(tan2, wrp[7], sp(0.f)); p7 = pkfma(nor2, wrn[7], p7);
    float rsum = fold8h(p0.x + p0.y, p1.x + p1.y, p2.x + p2.y, p3.x + p3.y,
                        p4.x + p4.y, p5.x + p5.y, p6.x + p6.y, p7.x + p7.y, hl);
    float r_l = fmaxf(rsum + br[j], 0.f);   // lane holds r[j], j = hl&7

    // broadcast within half: slot m holds r[j ^ m]
    float rb0 = r_l;
    float rb1 = __shfl_xor(rb0, 1, 64);
    float rb2 = __shfl_xor(rb0, 2, 64);
    float rb3 = __shfl_xor(rb1, 2, 64);
    float rb4 = __shfl_xor(rb0, 4, 64);
    float rb5 = __shfl_xor(rb1, 4, 64);
    float rb6 = __shfl_xor(rb2, 4, 64);
    float rb7 = __shfl_xor(rb3, 4, 64);

    // ---- w = sigmoid(we . r + be), packed channel pairs ----
    const char* web = (const char*)we;
    unsigned voff = ((unsigned)j << 9) | laneoff8;
    f2 zt2 = *(const f2*)((const char*)be + laneoff8);
    f2 zn2 = *(const f2*)((const char*)be + 256 + laneoff8);
#pragma unroll
    for (int m = 0; m < 8; ++m) {
        unsigned vm = voff ^ ((unsigned)m << 9);
        float rbm = (m == 0) ? rb0 : (m == 1) ? rb1 : (m == 2) ? rb2 : (m == 3) ? rb3
                  : (m == 4) ? rb4 : (m == 5) ? rb5 : (m == 6) ? rb6 : rb7;
        zt2 = pkfma(sp(rbm), *(const f2*)(web + vm), zt2);
        zn2 = pkfma(sp(rbm), *(const f2*)(web + vm + 256), zn2);
    }
    f2 wt2, wn2;
    wt2.x = __builtin_amdgcn_rcpf(1.f + __expf(-zt2.x));
    wt2.y = __builtin_amdgcn_rcpf(1.f + __expf(-zt2.y));
    wn2.x = __builtin_amdgcn_rcpf(1.f + __expf(-zn2.x));
    wn2.y = __builtin_amdgcn_rcpf(1.f + __expf(-zn2.y));

    // out byte = (pixelA_index << 8) + (lane << 3); halves = adjacent pixels
    f2 o = mk2((wt2.x + wn2.x) * xc2.x, (wt2.y + wn2.y) * xc2.y);
    size_t pixA = ((size_t)b << 16) + ((size_t)yqw << 8) + (size_t)(xq0 + ((wid & 1) << 1));
    *(f2*)((char*)out + (pixA << 8) + ((unsigned)lane << 3)) = o;
}

extern "C" void kernel_launch(void* const* d_in, const int* in_sizes, int n_in,
                              void* d_out, int out_size, void* d_ws, size_t ws_size,
                              hipStream_t stream) {
    const float* x  = (const float*)d_in[0];
    const float* w3 = (const float*)d_in[1];
    const float* b3 = (const float*)d_in[2];
    const float* w1 = (const float*)d_in[3];
    const float* b1 = (const float*)d_in[4];
    const float* wr = (const float*)d_in[5];
    const float* br = (const float*)d_in[6];
    const float* we = (const float*)d_in[7];
    const float* be = (const float*)d_in[8];
    float* out = (float*)d_out;
    f2* ws = (f2*)d_ws;

    repack_kernel<<<11, 256, 0, stream>>>(w3, wr, ws);

    // 524288 pixels / 8 per block = 65536 blocks of 256 threads
    dim3 grid(65536), block(256);
    oca_kernel<<<grid, block, 0, stream>>>(x, b3, w1, b1, br, we, be, ws, out);
}

// Round 12
// 955.398 us; speedup vs baseline: 1.1873x; 1.1851x over previous
//
#include <hip/hip_runtime.h>
#include <math.h>

#define PI_F 3.14159265358979323846f

// Lane returns the full-64-lane sum of v[lane&7].
// Phase A folds the value dim (strides 4,2,1); phase B sums groups (8,16,32).
__device__ __forceinline__ float fold8(float v0, float v1, float v2, float v3,
                                       float v4, float v5, float v6, float v7,
                                       int lane) {
    const bool b4 = (lane & 4) != 0;
    float k0 = b4 ? v4 : v0, g0 = b4 ? v0 : v4;
    float k1 = b4 ? v5 : v1, g1 = b4 ? v1 : v5;
    float k2 = b4 ? v6 : v2, g2 = b4 ? v2 : v6;
    float k3 = b4 ? v7 : v3, g3 = b4 ? v3 : v7;
    k0 += __shfl_xor(g0, 4, 64);
    k1 += __shfl_xor(g1, 4, 64);
    k2 += __shfl_xor(g2, 4, 64);
    k3 += __shfl_xor(g3, 4, 64);
    const bool b2 = (lane & 2) != 0;
    float m0 = b2 ? k2 : k0, n0 = b2 ? k0 : k2;
    float m1 = b2 ? k3 : k1, n1 = b2 ? k1 : k3;
    m0 += __shfl_xor(n0, 2, 64);
    m1 += __shfl_xor(n1, 2, 64);
    const bool b1_ = (lane & 1) != 0;
    float q = b1_ ? m1 : m0, r = b1_ ? m0 : m1;
    q += __shfl_xor(r, 1, 64);
    q += __shfl_xor(q, 8, 64);
    q += __shfl_xor(q, 16, 64);
    q += __shfl_xor(q, 32, 64);
    return q;
}

// Safe bilinear (borders): clipped-integer-corner weights, faithful to ref.
__device__ __forceinline__ float bilin_s(const float* __restrict__ img,
                                         float cy, float cx, int lane) {
    float fy0 = floorf(cy);
    float fx0 = floorf(cx);
    int y0 = __builtin_amdgcn_readfirstlane((int)fy0);
    int x0 = __builtin_amdgcn_readfirstlane((int)fx0);
    int y0i = min(max(y0, 0), 255);
    int x0i = min(max(x0, 0), 255);
    int y1i = min(max(y0 + 1, 0), 255);
    int x1i = min(max(x0 + 1, 0), 255);
    float wy0 = (float)y1i - cy;
    float wy1 = cy - (float)y0i;
    float wx0 = (float)x1i - cx;
    float wx1 = cx - (float)x0i;
    const float* pa = img + (size_t)(((y0i << 8) + x0i) << 6);
    const float* pb = img + (size_t)(((y1i << 8) + x0i) << 6);
    const float* pc = img + (size_t)(((y0i << 8) + x1i) << 6);
    const float* pd = img + (size_t)(((y1i << 8) + x1i) << 6);
    float Ia = pa[lane], Ib = pb[lane], Ic = pc[lane], Id = pd[lane];
    return (wx0 * wy0) * Ia + (wx0 * wy1) * Ib + (wx1 * wy0) * Ic + (wx1 * wy1) * Id;
}

// Fast bilinear (interior, coords guaranteed in [1, 254.999]): no clamps.
// Weights algebraically identical to the clipped form: y1f = fy+1, y0f = fy.
__device__ __forceinline__ float bilin_f(const float* __restrict__ img,
                                         float cy, float cx, int lane) {
    float fy = floorf(cy), fx = floorf(cx);
    int y0 = __builtin_amdgcn_readfirstlane((int)fy);
    int x0 = __builtin_amdgcn_readfirstlane((int)fx);
    float wy1 = cy - fy;
    float wy0 = (fy + 1.f) - cy;
    float wx1 = cx - fx;
    float wx0 = (fx + 1.f) - cx;
    const float* p00 = img + (size_t)(((y0 << 8) + x0) << 6);
    const float* p10 = p00 + (1 << 14);   // +1 image row (256 px * 64 ch)
    float Ia = p00[lane];
    float Ib = p10[lane];
    float Ic = p00[lane + 64];
    float Id = p10[lane + 64];
    return (wx0 * wy0) * Ia + (wx0 * wy1) * Ib + (wx1 * wy0) * Ic + (wx1 * wy1) * Id;
}

__global__ __launch_bounds__(256) void oca_kernel(
    const float* __restrict__ x,
    const float* __restrict__ w3, const float* __restrict__ b3,
    const float* __restrict__ w1, const float* __restrict__ b1,
    const float* __restrict__ wr, const float* __restrict__ br,
    const float* __restrict__ we, const float* __restrict__ be,
    float* __restrict__ out) {
    const int lane = threadIdx.x & 63;
    const int wid = __builtin_amdgcn_readfirstlane(blockIdx.x * 4 + (threadIdx.x >> 6));
    const int b  = wid >> 16;
    const int yq = (wid >> 8) & 255;
    const int xq = wid & 255;
    const float* img = x + ((size_t)b << 22);

    // wave-uniform interior test: pool coords stay in [1, 254.999] and conv
    // taps in [0,255] when pixel is in [5,250]^2
    const bool inner = (yq >= 5) && (yq <= 250) && (xq >= 5) && (xq <= 250);

    // ---- conv3x3 -> 8 hidden partials; lane = input channel ----
    float h0 = 0.f, h1 = 0.f, h2 = 0.f, h3 = 0.f;
    float h4 = 0.f, h5 = 0.f, h6 = 0.f, h7 = 0.f;
    float xc = 0.f;
    if (inner) {
        const float* base = img + (size_t)((((yq - 1) << 8) + (xq - 1)) << 6);
#pragma unroll
        for (int dy = 0; dy < 3; ++dy) {
#pragma unroll
            for (int dx = 0; dx < 3; ++dx) {
                float xv = base[(dy << 14) + (dx << 6) + lane];
                if (dy == 1 && dx == 1) xc = xv;
                const float* wp = w3 + (size_t)(((dy * 3 + dx) << 6) + lane) * 8;
                float4 w0 = *(const float4*)(wp);
                float4 w1v = *(const float4*)(wp + 4);
                h0 = fmaf(xv, w0.x, h0);
                h1 = fmaf(xv, w0.y, h1);
                h2 = fmaf(xv, w0.z, h2);
                h3 = fmaf(xv, w0.w, h3);
                h4 = fmaf(xv, w1v.x, h4);
                h5 = fmaf(xv, w1v.y, h5);
                h6 = fmaf(xv, w1v.z, h6);
                h7 = fmaf(xv, w1v.w, h7);
            }
        }
    } else {
#pragma unroll
        for (int dy = -1; dy <= 1; ++dy) {
            int yy = yq + dy;
            if ((unsigned)yy >= 256u) continue;
#pragma unroll
            for (int dx = -1; dx <= 1; ++dx) {
                int xx = xq + dx;
                if ((unsigned)xx >= 256u) continue;
                float xv = img[(size_t)(((yy << 8) + xx) << 6) + lane];
                if (dy == 0 && dx == 0) xc = xv;
                const float* wp = w3 + (size_t)((((dy + 1) * 3 + dx + 1) << 6) + lane) * 8;
                float4 w0 = *(const float4*)(wp);
                float4 w1v = *(const float4*)(wp + 4);
                h0 = fmaf(xv, w0.x, h0);
                h1 = fmaf(xv, w0.y, h1);
                h2 = fmaf(xv, w0.z, h2);
                h3 = fmaf(xv, w0.w, h3);
                h4 = fmaf(xv, w1v.x, h4);
                h5 = fmaf(xv, w1v.y, h5);
                h6 = fmaf(xv, w1v.z, h6);
                h7 = fmaf(xv, w1v.w, h7);
            }
        }
    }
    const int j = lane & 7;
    float hsum = fold8(h0, h1, h2, h3, h4, h5, h6, h7, lane);
    float h_l = fmaxf(hsum + b3[j], 0.f);   // lane holds h[j]

    // ---- theta = pi * sigmoid(w1 . h + b1) ----
    float zp = h_l * w1[j];
    zp += __shfl_xor(zp, 1, 64);
    zp += __shfl_xor(zp, 2, 64);
    zp += __shfl_xor(zp, 4, 64);
    float z = zp + b1[0];
    float theta = PI_F * __builtin_amdgcn_rcpf(1.f + __expf(-z));
    float ct = __cosf(theta);
    float st = __sinf(theta);

    // ---- oriented pooling ----
    const float fy = (float)yq, fx = (float)xq;
    float acc_t, acc_n;
    if (inner) {
        // t=0 sample of BOTH directions is exactly the center value
        acc_t = xc;
        acc_n = xc;
#pragma unroll
        for (int t = -4; t <= 4; ++t) {
            if (t == 0) continue;
            float tf = (float)t;
            acc_t += bilin_f(img, fmaf(tf, st, fy), fmaf(tf, ct, fx), lane);
            acc_n += bilin_f(img, fmaf(tf, ct, fy), fmaf(-tf, st, fx), lane);
        }
    } else {
        acc_t = 0.f;
        acc_n = 0.f;
#pragma unroll
        for (int t = -4; t <= 4; ++t) {
            float tf = (float)t;
            acc_t += bilin_s(img, fmaf(tf, st, fy), fmaf(tf, ct, fx), lane);
            acc_n += bilin_s(img, fmaf(tf, ct, fy), fmaf(-tf, st, fx), lane);
        }
    }
    float tanv = acc_t * (1.f / 9.f);
    float norv = acc_n * (1.f / 9.f);

    // ---- r = relu(wr . [tan;nor] + br) ----
    const float* wrp0 = wr + (size_t)lane * 8;
    const float* wrp1 = wr + (size_t)(64 + lane) * 8;
    float4 a0 = *(const float4*)(wrp0);
    float4 a1 = *(const float4*)(wrp0 + 4);
    float4 c0 = *(const float4*)(wrp1);
    float4 c1 = *(const float4*)(wrp1 + 4);
    float p0 = fmaf(tanv, a0.x, norv * c0.x);
    float p1 = fmaf(tanv, a0.y, norv * c0.y);
    float p2 = fmaf(tanv, a0.z, norv * c0.z);
    float p3 = fmaf(tanv, a0.w, norv * c0.w);
    float p4 = fmaf(tanv, a1.x, norv * c1.x);
    float p5 = fmaf(tanv, a1.y, norv * c1.y);
    float p6 = fmaf(tanv, a1.z, norv * c1.z);
    float p7 = fmaf(tanv, a1.w, norv * c1.w);
    float rsum = fold8(p0, p1, p2, p3, p4, p5, p6, p7, lane);
    float r_l = fmaxf(rsum + br[j], 0.f);   // lane holds r[j]

    // broadcast: slot m holds r[j ^ m]
    float rb0 = r_l;
    float rb1 = __shfl_xor(rb0, 1, 64);
    float rb2 = __shfl_xor(rb0, 2, 64);
    float rb3 = __shfl_xor(rb1, 2, 64);
    float rb4 = __shfl_xor(rb0, 4, 64);
    float rb5 = __shfl_xor(rb1, 4, 64);
    float rb6 = __shfl_xor(rb2, 4, 64);
    float rb7 = __shfl_xor(rb3, 4, 64);

    // ---- w = sigmoid(we . r + be); out = (w_tan + w_nor) * x ----
    // row (j^m): byte = ((j^m)<<9) + lane*4; +256B for the zn half
    const char* web = (const char*)we + ((unsigned)j << 9) + ((unsigned)lane << 2);
    float zt = be[lane];
    float zn = be[64 + lane];
    zt = fmaf(rb0, *(const float*)(web), zt);
    zn = fmaf(rb0, *(const float*)(web + 256), zn);
    zt = fmaf(rb1, *(const float*)((uintptr_t)web ^ (1u << 9)), zt);
    zn = fmaf(rb1, *(const float*)(((uintptr_t)web ^ (1u << 9)) + 256), zn);
    zt = fmaf(rb2, *(const float*)((uintptr_t)web ^ (2u << 9)), zt);
    zn = fmaf(rb2, *(const float*)(((uintptr_t)web ^ (2u << 9)) + 256), zn);
    zt = fmaf(rb3, *(const float*)((uintptr_t)web ^ (3u << 9)), zt);
    zn = fmaf(rb3, *(const float*)(((uintptr_t)web ^ (3u << 9)) + 256), zn);
    zt = fmaf(rb4, *(const float*)((uintptr_t)web ^ (4u << 9)), zt);
    zn = fmaf(rb4, *(const float*)(((uintptr_t)web ^ (4u << 9)) + 256), zn);
    zt = fmaf(rb5, *(const float*)((uintptr_t)web ^ (5u << 9)), zt);
    zn = fmaf(rb5, *(const float*)(((uintptr_t)web ^ (5u << 9)) + 256), zn);
    zt = fmaf(rb6, *(const float*)((uintptr_t)web ^ (6u << 9)), zt);
    zn = fmaf(rb6, *(const float*)(((uintptr_t)web ^ (6u << 9)) + 256), zn);
    zt = fmaf(rb7, *(const float*)((uintptr_t)web ^ (7u << 9)), zt);
    zn = fmaf(rb7, *(const float*)(((uintptr_t)web ^ (7u << 9)) + 256), zn);

    float wt = __builtin_amdgcn_rcpf(1.f + __expf(-zt));
    float wn = __builtin_amdgcn_rcpf(1.f + __expf(-zn));
    out[((size_t)wid << 6) + lane] = (wt + wn) * xc;
}

extern "C" void kernel_launch(void* const* d_in, const int* in_sizes, int n_in,
                              void* d_out, int out_size, void* d_ws, size_t ws_size,
                              hipStream_t stream) {
    const float* x  = (const float*)d_in[0];
    const float* w3 = (const float*)d_in[1];
    const float* b3 = (const float*)d_in[2];
    const float* w1 = (const float*)d_in[3];
    const float* b1 = (const float*)d_in[4];
    const float* wr = (const float*)d_in[5];
    const float* br = (const float*)d_in[6];
    const float* we = (const float*)d_in[7];
    const float* be = (const float*)d_in[8];
    float* out = (float*)d_out;

    const int total_waves = 8 * 256 * 256;   // one wave per pixel
    dim3 grid(total_waves / 4), block(256);  // 4 waves per block
    oca_kernel<<<grid, block, 0, stream>>>(x, w3, b3, w1, b1, wr, br, we, be, out);
}